// Round 6
// baseline (409.796 us; speedup 1.0000x reference)
//
#include <hip/hip_runtime.h>
#include <float.h>

#define N_NODES 50000
#define N_EDGES 600000
#define D 128
#define N_GRAPHS 64
#define SEG_CHUNK 32
#define SCAN_T 256
#define SCAN_NBLK ((N_NODES + SCAN_T - 1) / SCAN_T)   // 196

typedef __attribute__((ext_vector_type(8))) short short8;   // 8 bf16 = 4 VGPRs
typedef __attribute__((ext_vector_type(4))) float floatx4;

__device__ inline float bf2f(unsigned short h) {
    return __uint_as_float((unsigned)h << 16);
}
__device__ inline unsigned short f2bf(float f) {
    unsigned u = __float_as_uint(f);
    return (unsigned short)((u + 0x7fffu + ((u >> 16) & 1u)) >> 16);   // RNE
}

// ---------------- prep: zero deg + init pooled-max buffer ----------------------

__global__ void prep(int* __restrict__ deg, float* __restrict__ g) {
    int i = blockIdx.x * 256 + threadIdx.x;
    if (i < N_NODES) deg[i] = 0;
    if (i < N_GRAPHS * D) g[i] = -FLT_MAX;
}

// ---------------- casts: x -> bf16, and 3 weight pairs -> Bb[o][k] bf16 --------
// Bb row-major-in-k IS the MFMA B-fragment layout (n fixed, k contiguous).

__global__ void cast_all(const float4* __restrict__ x, ushort4* __restrict__ xb, int n4,
                         const float* __restrict__ Wr0, const float* __restrict__ Wo0,
                         const float* __restrict__ Wr1, const float* __restrict__ Wo1,
                         const float* __restrict__ Wr2, const float* __restrict__ Wo2,
                         unsigned short* __restrict__ B0, unsigned short* __restrict__ B1,
                         unsigned short* __restrict__ B2) {
    int idx = blockIdx.x * 256 + threadIdx.x;
    if (idx < n4) {
        float4 v = x[idx];
        ushort4 o;
        o.x = f2bf(v.x); o.y = f2bf(v.y); o.z = f2bf(v.z); o.w = f2bf(v.w);
        xb[idx] = o;
        return;
    }
    int w = idx - n4;                        // 0 .. 3*32768-1
    if (w >= 3 * 128 * 256) return;
    int l = w >> 15;
    int r = w & 32767;
    int o = r >> 8, k = r & 255;
    const float* Wr = (l == 0) ? Wr0 : (l == 1) ? Wr1 : Wr2;
    const float* Wo = (l == 0) ? Wo0 : (l == 1) ? Wo1 : Wo2;
    unsigned short* B = (l == 0) ? B0 : (l == 1) ? B1 : B2;
    float v = (k < 128) ? Wr[o * 128 + k] : Wo[o * 128 + (k - 128)];
    B[r] = f2bf(v);
}

// ---------------- CSR build (once per launch) ----------------------------------

__global__ void count_deg(const int* __restrict__ ei, int* __restrict__ deg) {
    int e = blockIdx.x * 256 + threadIdx.x;
    if (e < N_EDGES) atomicAdd(&deg[ei[N_EDGES + e]], 1);
}

__global__ __launch_bounds__(SCAN_T) void block_sum(const int* __restrict__ deg,
                                                    int* __restrict__ blockSums) {
    __shared__ int s[SCAN_T];
    int tid = threadIdx.x;
    int i = blockIdx.x * SCAN_T + tid;
    s[tid] = (i < N_NODES) ? deg[i] : 0;
    __syncthreads();
    for (int off = SCAN_T / 2; off > 0; off >>= 1) {
        if (tid < off) s[tid] += s[tid + off];
        __syncthreads();
    }
    if (tid == 0) blockSums[blockIdx.x] = s[0];
}

__global__ __launch_bounds__(SCAN_T) void scan_blocks(const int* __restrict__ blockSums,
                                                      int* __restrict__ blockOff,
                                                      int* __restrict__ row_start) {
    __shared__ int s[SCAN_T];
    int tid = threadIdx.x;
    int v = (tid < SCAN_NBLK) ? blockSums[tid] : 0;
    s[tid] = v;
    __syncthreads();
    for (int off = 1; off < SCAN_T; off <<= 1) {
        int t = (tid >= off) ? s[tid - off] : 0;
        __syncthreads();
        s[tid] += t;
        __syncthreads();
    }
    if (tid < SCAN_NBLK) blockOff[tid] = s[tid] - v;
    if (tid == SCAN_T - 1) row_start[N_NODES] = s[tid];
}

__global__ __launch_bounds__(SCAN_T) void scan_write(const int* __restrict__ deg,
                                                     const int* __restrict__ blockOff,
                                                     int* __restrict__ row_start,
                                                     int* __restrict__ cursor) {
    __shared__ int s[SCAN_T];
    int tid = threadIdx.x;
    int i = blockIdx.x * SCAN_T + tid;
    int v = (i < N_NODES) ? deg[i] : 0;
    s[tid] = v;
    __syncthreads();
    for (int off = 1; off < SCAN_T; off <<= 1) {
        int t = (tid >= off) ? s[tid - off] : 0;
        __syncthreads();
        s[tid] += t;
        __syncthreads();
    }
    if (i < N_NODES) {
        int rs = blockOff[blockIdx.x] + s[tid] - v;
        row_start[i] = rs;
        cursor[i]    = rs;
    }
}

__global__ void fill_csr(const int* __restrict__ ei, int* __restrict__ cursor,
                         int* __restrict__ csr_src) {
    int e = blockIdx.x * 256 + threadIdx.x;
    if (e < N_EDGES) {
        int dst = ei[N_EDGES + e];
        int pos = atomicAdd(&cursor[dst], 1);
        csr_src[pos] = ei[e];
    }
}

// ---------------- fused layer: gather (register-resident) + MFMA GEMM ----------
// O = [agg | x] @ Bb^T + bias, agg[i] = sum_{j->i} x[j].
// Lane (m,quad) of each wave owns A-row row0+m, features {ks*32+quad*8..+8},
// ks=0..3 — exactly the MFMA A-fragment slice. It gathers those 32 features
// over the row's neighbors into 32 fp32 regs, converts to 4 bf16 a-frags, and
// feeds MFMA directly: no LDS, no agg buffer, no extra kernel.

__global__ __launch_bounds__(256) void layer_fused(
    const unsigned short* __restrict__ xb,
    const int* __restrict__ row_start, const int* __restrict__ csr_src,
    const unsigned short* __restrict__ Bb, const float* __restrict__ bias,
    unsigned short* __restrict__ Ob, int relu)
{
    int tid  = threadIdx.x;
    int wave = tid >> 6;
    int lane = tid & 63;
    int m    = lane & 15;
    int quad = lane >> 4;
    int row0 = blockIdx.x * 64 + wave * 16;
    int arow = row0 + m;
    int crow = (arow < N_NODES) ? arow : (N_NODES - 1);   // clamp; stores guarded

    // ---- gather phase: 32 fp32 accumulators = this lane's A-fragment slice ----
    float ga[4][8];
#pragma unroll
    for (int c = 0; c < 4; ++c)
#pragma unroll
        for (int j = 0; j < 8; ++j) ga[c][j] = 0.f;

    int beg = row_start[crow];
    int end = (arow < N_NODES) ? row_start[crow + 1] : beg;
    for (int i = beg; i < end; ++i) {
        int s = csr_src[i];
        const unsigned short* xr = xb + (size_t)s * D + quad * 8;
#pragma unroll
        for (int c = 0; c < 4; ++c) {
            short8 u = *(const short8*)(xr + c * 32);
#pragma unroll
            for (int j = 0; j < 8; ++j) ga[c][j] += bf2f((unsigned short)u[j]);
        }
    }

    // convert to bf16 a-fragments (k = ks*32 + quad*8 .. +8)
    short8 afrag[4];
#pragma unroll
    for (int c = 0; c < 4; ++c)
#pragma unroll
        for (int j = 0; j < 8; ++j) afrag[c][j] = (short)f2bf(ga[c][j]);

    // ---- MFMA phase ----
    floatx4 acc[8];
#pragma unroll
    for (int t = 0; t < 8; ++t) acc[t] = (floatx4){0.f, 0.f, 0.f, 0.f};

#pragma unroll
    for (int ks = 0; ks < 4; ++ks) {                 // K 0..127: agg half
#pragma unroll
        for (int t = 0; t < 8; ++t) {
            short8 b = *(const short8*)(Bb + (size_t)(t * 16 + m) * 256 + ks * 32 + quad * 8);
            acc[t] = __builtin_amdgcn_mfma_f32_16x16x32_bf16(afrag[ks], b, acc[t], 0, 0, 0);
        }
    }
#pragma unroll
    for (int ks = 4; ks < 8; ++ks) {                 // K 128..255: root-x half
        short8 a = *(const short8*)(xb + (size_t)crow * D + (ks - 4) * 32 + quad * 8);
#pragma unroll
        for (int t = 0; t < 8; ++t) {
            short8 b = *(const short8*)(Bb + (size_t)(t * 16 + m) * 256 + ks * 32 + quad * 8);
            acc[t] = __builtin_amdgcn_mfma_f32_16x16x32_bf16(a, b, acc[t], 0, 0, 0);
        }
    }

    // ---- epilogue: C/D mapping col=lane&15, row=quad*4+reg ----
#pragma unroll
    for (int t = 0; t < 8; ++t) {
        int col = t * 16 + m;
        float bv = bias[col];
#pragma unroll
        for (int r = 0; r < 4; ++r) {
            int row = row0 + quad * 4 + r;
            if (row >= N_NODES) continue;
            float v = acc[t][r] + bv;
            if (relu) v = fmaxf(v, 0.f);
            Ob[(size_t)row * D + col] = f2bf(v);
        }
    }
}

// ---------------- pooling + head ----------------------------------------------

__device__ inline void atomicMaxF(float* addr, float v) {
    if (v >= 0.f) atomicMax((int*)addr, __float_as_int(v));
    else          atomicMin((unsigned int*)addr, __float_as_uint(v));
}

__global__ __launch_bounds__(128) void seg_max(const unsigned short* __restrict__ h,
                                               const int* __restrict__ batch,
                                               float* __restrict__ g) {
    int d  = threadIdx.x;
    int n0 = blockIdx.x * SEG_CHUNK;
    int nend = min(n0 + SEG_CHUNK, N_NODES);
    int cur_b = batch[n0];
    float cur = -FLT_MAX;
    for (int n = n0; n < nend; ++n) {
        int b = batch[n];
        if (b != cur_b) {
            atomicMaxF(&g[cur_b * D + d], cur);
            cur_b = b;
            cur = -FLT_MAX;
        }
        cur = fmaxf(cur, bf2f(h[(size_t)n * D + d]));
    }
    atomicMaxF(&g[cur_b * D + d], cur);
}

__global__ void mlp_head(const float* __restrict__ g,
                         const float* __restrict__ W1, const float* __restrict__ b1,
                         const float* __restrict__ W2, const float* __restrict__ b2,
                         float* __restrict__ out) {
    int gi = threadIdx.x;
    if (gi >= N_GRAPHS) return;
    float h[5];
#pragma unroll
    for (int j = 0; j < 5; ++j) {
        float acc = b1[j];
        for (int k = 0; k < D; ++k) acc += g[gi * D + k] * W1[j * D + k];
        h[j] = fmaxf(acc, 0.f);
    }
    float o = b2[0];
#pragma unroll
    for (int j = 0; j < 5; ++j) o += h[j] * W2[j];
    out[gi] = o;
}

extern "C" void kernel_launch(void* const* d_in, const int* in_sizes, int n_in,
                              void* d_out, int out_size, void* d_ws, size_t ws_size,
                              hipStream_t stream) {
    const float* x     = (const float*)d_in[0];
    const int*   ei    = (const int*)d_in[1];
    const int*   batch = (const int*)d_in[2];
    const float* Wrel[3]  = {(const float*)d_in[3], (const float*)d_in[6], (const float*)d_in[9]};
    const float* brel[3]  = {(const float*)d_in[4], (const float*)d_in[7], (const float*)d_in[10]};
    const float* Wroot[3] = {(const float*)d_in[5], (const float*)d_in[8], (const float*)d_in[11]};
    const float* W1 = (const float*)d_in[12];
    const float* b1 = (const float*)d_in[13];
    const float* W2 = (const float*)d_in[14];
    const float* b2 = (const float*)d_in[15];
    float* out = (float*)d_out;

    char* ws = (char*)d_ws;
    const size_t nodeB16 = (size_t)N_NODES * D * sizeof(unsigned short);   // 12.8 MB
    unsigned short* xb  = (unsigned short*)(ws);
    unsigned short* hb1 = (unsigned short*)(ws + nodeB16);
    unsigned short* hb2 = (unsigned short*)(ws + 2 * nodeB16);
    char* p = ws + 3 * nodeB16;
    unsigned short* Bb0 = (unsigned short*)p;   p += 128 * 256 * sizeof(unsigned short);
    unsigned short* Bb1 = (unsigned short*)p;   p += 128 * 256 * sizeof(unsigned short);
    unsigned short* Bb2 = (unsigned short*)p;   p += 128 * 256 * sizeof(unsigned short);
    float* g        = (float*)p;                p += N_GRAPHS * D * sizeof(float);
    int*   deg      = (int*)p;                  p += N_NODES * sizeof(int);
    int*   row_start= (int*)p;                  p += (N_NODES + 1) * sizeof(int);
    int*   cursor   = (int*)p;                  p += N_NODES * sizeof(int);
    int*   csr_src  = (int*)p;                  p += N_EDGES * sizeof(int);
    int*   blockSums= (int*)p;                  p += SCAN_NBLK * sizeof(int);
    int*   blockOff = (int*)p;                  p += SCAN_NBLK * sizeof(int);
    unsigned short* Bb[3] = {Bb0, Bb1, Bb2};

    // prep + CSR build (once per call)
    prep<<<SCAN_NBLK, 256, 0, stream>>>(deg, g);
    count_deg<<<(N_EDGES + 255) / 256, 256, 0, stream>>>(ei, deg);
    block_sum<<<SCAN_NBLK, SCAN_T, 0, stream>>>(deg, blockSums);
    scan_blocks<<<1, SCAN_T, 0, stream>>>(blockSums, blockOff, row_start);
    scan_write<<<SCAN_NBLK, SCAN_T, 0, stream>>>(deg, blockOff, row_start, cursor);
    fill_csr<<<(N_EDGES + 255) / 256, 256, 0, stream>>>(ei, cursor, csr_src);

    // bf16 conversions (x + all 3 weight pairs, one kernel)
    const int n4 = N_NODES * D / 4;                       // 1.6M
    const int cast_total = n4 + 3 * 128 * 256;
    cast_all<<<(cast_total + 255) / 256, 256, 0, stream>>>(
        (const float4*)x, (ushort4*)xb, n4,
        Wrel[0], Wroot[0], Wrel[1], Wroot[1], Wrel[2], Wroot[2],
        Bb0, Bb1, Bb2);

    const unsigned short* cur = xb;
    unsigned short* outs[3] = {hb1, hb2, hb1};
    const int grid = (N_NODES + 63) / 64;                 // 782
    for (int l = 0; l < 3; ++l) {
        layer_fused<<<grid, 256, 0, stream>>>(cur, row_start, csr_src, Bb[l], brel[l],
                                              outs[l], (l < 2) ? 1 : 0);
        cur = outs[l];
    }

    seg_max<<<(N_NODES + SEG_CHUNK - 1) / SEG_CHUNK, 128, 0, stream>>>(cur, batch, g);
    mlp_head<<<1, 64, 0, stream>>>(g, W1, b1, W2, b2, out);
}